// Round 14
// baseline (504.871 us; speedup 1.0000x reference)
//
#include <hip/hip_runtime.h>
#include <hip/hip_bf16.h>
#include <cstdint>
#include <cstddef>

typedef __bf16 bf16;
typedef __bf16 bf16x4 __attribute__((ext_vector_type(4)));
typedef __bf16 bf16x8 __attribute__((ext_vector_type(8)));
typedef float  f32x4  __attribute__((ext_vector_type(4)));

#define S_LEN 2048
#define HID   4096
#define NH    32
#define NKV   8
#define HD    128
#define QLD   6144   // QKV buffer row stride (Q cols 0..4095, K 4096..5119, V 5120..6143)
#define KVLD  6144

// ---------------------------------------------------------------------------
// async global->LDS, 16B per lane. LDS dest is wave-uniform base + lane*16.
__device__ __forceinline__ void gload_lds16(const bf16* g, bf16* l) {
    __builtin_amdgcn_global_load_lds(
        (const __attribute__((address_space(1))) void*)g,
        (__attribute__((address_space(3))) void*)l,
        16, 0, 0);
}

// ---------------------------------------------------------------------------
// fp32 -> bf16 cast (vectorized float4 -> bf16x4)
__global__ void cast_f32_bf16(const float* __restrict__ in, bf16* __restrict__ out, int n4) {
    int idx    = blockIdx.x * blockDim.x + threadIdx.x;
    int stride = gridDim.x * blockDim.x;
    for (int i = idx; i < n4; i += stride) {
        float4 v = ((const float4*)in)[i];
        bf16x4 o = { (bf16)v.x, (bf16)v.y, (bf16)v.z, (bf16)v.w };
        ((bf16x4*)out)[i] = o;
    }
}

// ---------------------------------------------------------------------------
// GEMM: C[m][n] = sum_k A[m][k] * B[n][k]  (unchanged from R13: 128x128 tile,
// BK=64, dbuf LDS, 2-phase pipeline, XCD-chunked m-fast block order).
template <typename OUT_T>
__global__ __launch_bounds__(256) void gemm_bt(const bf16* __restrict__ A,
                                               const bf16* __restrict__ B,
                                               OUT_T* __restrict__ C,
                                               int M, int N, int K) {
    __shared__ alignas(16) bf16 sA[2][128 * 64];
    __shared__ alignas(16) bf16 sB[2][128 * 64];

    const int tid  = threadIdx.x;
    const int lane = tid & 63;
    const int w    = tid >> 6;      // 0..3
    const int wr   = w >> 1;        // wave row (0..1)
    const int wc   = w & 1;         // wave col (0..1)
    const int l15  = lane & 15;
    const int l4   = lane >> 4;
    const int mt   = M >> 7;                       // m-tiles
    const int cpx  = (int)gridDim.x >> 3;          // blocks per XCD chunk
    const int vb   = (blockIdx.x & 7) * cpx + (blockIdx.x >> 3);  // XCD-chunked
    const int m0   = (vb % mt) * 128;              // m fastest within chunk
    const int n0   = (vb / mt) * 128;

    f32x4 acc[4][4] = {};

    const int rsub = lane >> 3;                       // row within chunk (0..7)
    const int scol = ((lane & 7) * 8) ^ (rsub << 3);  // pre-swizzled source col

    auto stage = [&](int t, int buf) {
#pragma unroll
        for (int j = 0; j < 4; ++j) {
            const int c   = w * 4 + j;
            const int row = c * 8 + rsub;
            gload_lds16(A + (size_t)(m0 + row) * K + t * 64 + scol, &sA[buf][c * 512]);
            gload_lds16(B + (size_t)(n0 + row) * K + t * 64 + scol, &sB[buf][c * 512]);
        }
    };

    const int nt = K >> 6;   // K-tiles of 64

    stage(0, 0);
    __syncthreads();         // implicit vmcnt(0) drain

    int buf = 0;
    for (int t = 0; t < nt; ++t) {
        if (t + 1 < nt) stage(t + 1, buf ^ 1);   // prefetch hides under compute

        bf16x8 af[2][4], bfr[2][4];
#pragma unroll
        for (int kk = 0; kk < 2; ++kk) {
#pragma unroll
            for (int i = 0; i < 4; ++i) {
                const int ra = wr * 64 + i * 16 + l15;
                af[kk][i]  = *(const bf16x8*)&sA[buf][ra * 64 + ((kk * 32 + l4 * 8) ^ ((ra & 7) << 3))];
                const int rb = wc * 64 + i * 16 + l15;
                bfr[kk][i] = *(const bf16x8*)&sB[buf][rb * 64 + ((kk * 32 + l4 * 8) ^ ((rb & 7) << 3))];
            }
        }
#pragma unroll
        for (int kk = 0; kk < 2; ++kk)
#pragma unroll
            for (int i = 0; i < 4; ++i)
#pragma unroll
                for (int j = 0; j < 4; ++j)
                    acc[i][j] = __builtin_amdgcn_mfma_f32_16x16x32_bf16(af[kk][i], bfr[kk][j], acc[i][j], 0, 0, 0);

        __syncthreads();     // drains vmcnt (prefetch done); protects buf reuse
        buf ^= 1;
    }

    // epilogue: C/D layout col = lane&15, row = (lane>>4)*4 + reg
#pragma unroll
    for (int i = 0; i < 4; ++i) {
        const int row = m0 + wr * 64 + i * 16 + l4 * 4;
#pragma unroll
        for (int j = 0; j < 4; ++j) {
            const int col = n0 + wc * 64 + j * 16 + l15;
#pragma unroll
            for (int r = 0; r < 4; ++r)
                C[(size_t)(row + r) * N + col] = (OUT_T)acc[i][j][r];
        }
    }
}

// ---------------------------------------------------------------------------
// Flash attention, causal, GQA 4:1. R9 topology (8 waves/512 thr, strips b &
// 15-b of 128 q-rows, 16 rows/wave/strip, grid 8x32) with KVBLK=128: each
// barrier interval covers a 128-row K/V tile -> HALF the barriers, 2x MFMA
// per cluster (the axis that has consistently won). LDS 128KB: K dbuf 2x32K
// (gload_lds, pre-swizzled source) + V dbuf 2x32K (reg-staged transposed
// write). P (32KB) OVERLAYS sVt[cur^1]: P is dead by the time the V-prefetch
// write lands there, and writeV is remapped so wave w writes exactly d-rows
// [16w,16w+16) = its own P region (race-free per wave program order).
// No-max softmax; T5 setprio on MFMA clusters.
__global__ __launch_bounds__(512) void attn_kernel(const bf16* __restrict__ Q,
                                                   const bf16* __restrict__ Kp,
                                                   const bf16* __restrict__ Vp,
                                                   bf16* __restrict__ O) {
    __shared__ alignas(16) bf16 sK[2][128 * 128];   // [s][d], elem col ^= (row&7)<<3
    __shared__ alignas(16) bf16 sVt[2][128 * 128];  // [d][s], col within 64-half ^= (d&7)<<3

    const int tid  = threadIdx.x;
    const int lane = tid & 63;
    const int w    = tid >> 6;       // 0..7
    const int l15  = lane & 15;
    const int l4   = lane >> 4;
    const int h    = blockIdx.y;
    const int hk   = h >> 2;
    const int b    = blockIdx.x;                 // 0..7
    const int qH   = 15 - b;                     // heavy strip (128-row strips)
    const int qL   = b;                          // light strip
    const float C2 = 0.12751744f;                // scale * log2(e)

    const bf16* Kbase = Kp + hk * HD;
    const bf16* Vbase = Vp + hk * HD;

    // Q fragments for both strips (held in registers for whole kernel)
    const int rbH = qH * 128 + w * 16;
    const int rbL = qL * 128 + w * 16;
    bf16x8 qfH[4], qfL[4];
#pragma unroll
    for (int ks = 0; ks < 4; ++ks) {
        qfH[ks] = *(const bf16x8*)(Q + (size_t)(rbH + l15) * QLD + h * HD + ks * 32 + l4 * 8);
        qfL[ks] = *(const bf16x8*)(Q + (size_t)(rbL + l15) * QLD + h * HD + ks * 32 + l4 * 8);
    }

    f32x4 accH[8] = {}, accL[8] = {};
    float lH[4] = {0.f, 0.f, 0.f, 0.f}, lL[4] = {0.f, 0.f, 0.f, 0.f};

    // --- staging helpers (split across 8 waves) ---
    // K tile 128x128 = 32 chunks of 1KB (4 rows each); wave w stages 4 chunks.
    auto stageK = [&](int t, int buf) {
#pragma unroll
        for (int j = 0; j < 4; ++j) {
            const int c   = w * 4 + j;        // 0..31
            const int row = c * 4 + l4;       // 0..127
            const int col = (l15 * 8) ^ ((row & 7) << 3);
            gload_lds16(Kbase + (size_t)(t * 128 + row) * KVLD + col, &sK[buf][c * 512]);
        }
    };
    // V: wave w owns d-cols [16w,16w+16). 4 loads: half i&1 (s rows), group i>>1.
    auto loadV = [&](int t, bf16x8* vr) {
#pragma unroll
        for (int i = 0; i < 4; ++i) {
            const int s = (i & 1) * 64 + lane;
            const int g = i >> 1;
            vr[i] = *(const bf16x8*)(Vbase + (size_t)(t * 128 + s) * KVLD + 16 * w + g * 8);
        }
    };
    auto writeV = [&](const bf16x8* vr, int buf) {
#pragma unroll
        for (int i = 0; i < 4; ++i) {
            const int shalf = (i & 1) * 64;
            const int g     = i >> 1;
#pragma unroll
            for (int e = 0; e < 8; ++e) {
                const int d = 16 * w + g * 8 + e;          // d&7 == e
                sVt[buf][d * 128 + shalf + (lane ^ (e << 3))] = vr[i][e];
            }
        }
    };

    // --- one strip's QK^T/softmax/PV for one 128-wide tile ---
    auto strip = [&](const bf16x8* qf, f32x4* acc_o, float* lrow,
                     int rbase, int s0, int cur, bf16* sPw) {
        // QK^T: 16 q-rows x 128 s-cols (raw scores)
        f32x4 accs[8] = {};
        __builtin_amdgcn_s_setprio(1);
#pragma unroll
        for (int ks = 0; ks < 4; ++ks) {
#pragma unroll
            for (int j = 0; j < 8; ++j) {
                const int krow = j * 16 + l15;
                bf16x8 kb = *(const bf16x8*)&sK[cur][krow * 128 + ((ks * 32 + l4 * 8) ^ ((krow & 7) << 3))];
                accs[j] = __builtin_amdgcn_mfma_f32_16x16x32_bf16(qf[ks], kb, accs[j], 0, 0, 0);
            }
        }
        __builtin_amdgcn_s_setprio(0);

        // no-max softmax: p = exp2(raw*C2) (shift-invariant; raw bounded).
        float sc[8][4];
        float rsum[4] = {0.f, 0.f, 0.f, 0.f};
        const bool needMask = (s0 + 127 > rbase);   // wave-uniform
        if (needMask) {
#pragma unroll
            for (int j = 0; j < 8; ++j) {
                const int scol = s0 + j * 16 + l15;
#pragma unroll
                for (int i = 0; i < 4; ++i) {
                    const int r = rbase + l4 * 4 + i;
                    const float p = (scol > r) ? 0.f : exp2f(accs[j][i] * C2);
                    sc[j][i] = p;
                    rsum[i] += p;
                }
            }
        } else {
#pragma unroll
            for (int j = 0; j < 8; ++j)
#pragma unroll
                for (int i = 0; i < 4; ++i) {
                    const float p = exp2f(accs[j][i] * C2);
                    sc[j][i] = p;
                    rsum[i] += p;
                }
        }
        // row-sum reduce across the 16 lanes holding this row group
#pragma unroll
        for (int i = 0; i < 4; ++i) {
#pragma unroll
            for (int msk = 1; msk < 16; msk <<= 1)
                rsum[i] += __shfl_xor(rsum[i], msk);
            lrow[i] += rsum[i];
        }

        // P -> per-wave 4KB region (overlay; wave-private, in-wave ordering)
#pragma unroll
        for (int j = 0; j < 8; ++j)
#pragma unroll
            for (int i = 0; i < 4; ++i) {
                const int prow = l4 * 4 + i;
                const int s2   = (prow & 7) ^ ((prow >> 3) << 1);
                sPw[prow * 128 + ((j * 16 + l15) ^ (s2 << 3))] = (bf16)sc[j][i];
            }

        // PV: out[16][128] += P[16][128] * V[128][128]
        __builtin_amdgcn_s_setprio(1);
        const int s2l = (l15 & 7) ^ ((l15 >> 3) << 1);
#pragma unroll
        for (int kk = 0; kk < 4; ++kk) {
            bf16x8 pa = *(const bf16x8*)&sPw[l15 * 128 + ((kk * 32 + l4 * 8) ^ (s2l << 3))];
#pragma unroll
            for (int d = 0; d < 8; ++d) {
                const int vrow = d * 16 + l15;
                bf16x8 vbf = *(const bf16x8*)&sVt[cur][vrow * 128 + ((kk * 32 + l4 * 8) ^ ((vrow & 7) << 3))];
                acc_o[d] = __builtin_amdgcn_mfma_f32_16x16x32_bf16(pa, vbf, acc_o[d], 0, 0, 0);
            }
        }
        __builtin_amdgcn_s_setprio(0);
    };

    const int ntH = qH + 1;   // 128-wide tiles for heavy strip (= loop bound)
    const int ntL = qL + 1;   // tiles for light strip

    // prologue: stage tile 0 into buf 0
    bf16x8 vreg[4];
    loadV(0, vreg);
    stageK(0, 0);
    writeV(vreg, 0);
    __syncthreads();

    int cur = 0;
    for (int t = 0; t < ntH; ++t) {
        const int s0 = t * 128;
        const bool pf = (t + 1 < ntH);
        if (pf) {               // issue next-tile loads early (latency hides under compute)
            loadV(t + 1, vreg); // V first: its reg-use wait leaves K gload_lds in flight
            stageK(t + 1, cur ^ 1);
        }

        bf16* sPw = &sVt[cur ^ 1][0] + (w << 11);   // P overlay: wave's 4KB

        strip(qfH, accH, lH, rbH, s0, cur, sPw);
        if (t < ntL) strip(qfL, accL, lL, rbL, s0, cur, sPw);

        // write prefetched V into the other buffer (clobbers only this wave's
        // own dead P region -- d-rows [16w,16w+16))
        if (pf) writeV(vreg, cur ^ 1);

        __syncthreads();   // drains vmcnt (K gload_lds) + lgkm; buffers swap
        cur ^= 1;
    }

    // epilogue: normalize (reciprocal) and store both strips
    float rH[4], rL[4];
#pragma unroll
    for (int i = 0; i < 4; ++i) { rH[i] = __frcp_rn(lH[i]); rL[i] = __frcp_rn(lL[i]); }
#pragma unroll
    for (int d = 0; d < 8; ++d)
#pragma unroll
        for (int i = 0; i < 4; ++i) {
            O[(size_t)(rbH + l4 * 4 + i) * HID + h * HD + d * 16 + l15] = (bf16)(accH[d][i] * rH[i]);
            O[(size_t)(rbL + l4 * 4 + i) * HID + h * HD + d * 16 + l15] = (bf16)(accL[d][i] * rL[i]);
        }
}

// ---------------------------------------------------------------------------
extern "C" void kernel_launch(void* const* d_in, const int* in_sizes, int n_in,
                              void* d_out, int out_size, void* d_ws, size_t ws_size,
                              hipStream_t stream) {
    const float* hx = (const float*)d_in[0];
    // d_in[1] = attention_mask (exact causal) -- applied analytically
    const float* wq = (const float*)d_in[2];
    const float* wk = (const float*)d_in[3];
    const float* wv = (const float*)d_in[4];
    const float* wo = (const float*)d_in[5];
    float* out = (float*)d_out;

    // workspace layout (bf16), 92.3 MB total:
    //   Xb/Ob : 2048*4096  (X for projections; overwritten by attn output O)
    //   Wqkv  : 6144*4096  (wq rows 0..4095 | wk 4096..5119 | wv 5120..6143;
    //                       later reused for wo)
    //   QKV   : 2048*6144  (Q cols 0..4095 | K 4096..5119 | V 5120..6143)
    bf16* Xb   = (bf16*)d_ws;            // also Ob after attn
    bf16* Wqkv = Xb + 8388608;
    bf16* QKV  = Wqkv + 25165824;

    auto cast = [&](const float* src, bf16* dst, int n) {
        int n4 = n / 4;
        int blocks = (n4 + 255) / 256;
        if (blocks > 2048) blocks = 2048;
        cast_f32_bf16<<<blocks, 256, 0, stream>>>(src, dst, n4);
    };

    cast(hx, Xb, 2048 * 4096);
    cast(wq, Wqkv, 4096 * 4096);
    cast(wk, Wqkv + 16777216, 1024 * 4096);
    cast(wv, Wqkv + 20971520, 1024 * 4096);

    // single merged Q|K|V projection: N=6144, 768 blocks (XCD-chunked order)
    gemm_bt<bf16><<<dim3(768), 256, 0, stream>>>(Xb, Wqkv, QKV, 2048, 6144, 4096);

    // wo cast overwrites the (now dead) wq region
    cast(wo, Wqkv, 4096 * 4096);

    // attn reads QKV (stride 6144), writes O into Xb (X is dead now)
    attn_kernel<<<dim3(8, 32), 512, 0, stream>>>(QKV, QKV + 4096, QKV + 5120, Xb);

    gemm_bt<float><<<dim3(512), 256, 0, stream>>>(Xb, Wqkv, out, 2048, 4096, 4096);
}

// Round 15
// 317.081 us; speedup vs baseline: 1.5922x; 1.5922x over previous
//
#include <hip/hip_runtime.h>
#include <hip/hip_bf16.h>
#include <cstdint>
#include <cstddef>

typedef __bf16 bf16;
typedef __bf16 bf16x4 __attribute__((ext_vector_type(4)));
typedef __bf16 bf16x8 __attribute__((ext_vector_type(8)));
typedef float  f32x4  __attribute__((ext_vector_type(4)));

#define S_LEN 2048
#define HID   4096
#define NH    32
#define NKV   8
#define HD    128
#define QLD   6144   // QKV buffer row stride (Q cols 0..4095, K 4096..5119, V 5120..6143)
#define KVLD  6144

// ---------------------------------------------------------------------------
// async global->LDS, 16B per lane. LDS dest is wave-uniform base + lane*16.
__device__ __forceinline__ void gload_lds16(const bf16* g, bf16* l) {
    __builtin_amdgcn_global_load_lds(
        (const __attribute__((address_space(1))) void*)g,
        (__attribute__((address_space(3))) void*)l,
        16, 0, 0);
}

// ---------------------------------------------------------------------------
// fp32 -> bf16 cast (vectorized float4 -> bf16x4)
__global__ void cast_f32_bf16(const float* __restrict__ in, bf16* __restrict__ out, int n4) {
    int idx    = blockIdx.x * blockDim.x + threadIdx.x;
    int stride = gridDim.x * blockDim.x;
    for (int i = idx; i < n4; i += stride) {
        float4 v = ((const float4*)in)[i];
        bf16x4 o = { (bf16)v.x, (bf16)v.y, (bf16)v.z, (bf16)v.w };
        ((bf16x4*)out)[i] = o;
    }
}

// three-source cast into one contiguous dest (wq|wk|wv -> Wqkv): saves two
// kernel launches; branch is wave-uniform except at the two region seams.
__global__ void cast3_f32_bf16(const float* __restrict__ a, const float* __restrict__ b,
                               const float* __restrict__ c, bf16* __restrict__ out,
                               int na4, int nb4, int nc4) {
    int idx    = blockIdx.x * blockDim.x + threadIdx.x;
    int stride = gridDim.x * blockDim.x;
    const int total = na4 + nb4 + nc4;
    for (int i = idx; i < total; i += stride) {
        float4 v;
        if (i < na4)            v = ((const float4*)a)[i];
        else if (i < na4 + nb4) v = ((const float4*)b)[i - na4];
        else                    v = ((const float4*)c)[i - na4 - nb4];
        bf16x4 o = { (bf16)v.x, (bf16)v.y, (bf16)v.z, (bf16)v.w };
        ((bf16x4*)out)[i] = o;
    }
}

// ---------------------------------------------------------------------------
// GEMM: C[m][n] = sum_k A[m][k] * B[n][k]  (R13 proven: 128x128 tile, BK=64,
// dbuf LDS, 2-phase pipeline, XCD-chunked m-fast block order; ~941 TF = this
// structure's ceiling).
template <typename OUT_T>
__global__ __launch_bounds__(256) void gemm_bt(const bf16* __restrict__ A,
                                               const bf16* __restrict__ B,
                                               OUT_T* __restrict__ C,
                                               int M, int N, int K) {
    __shared__ alignas(16) bf16 sA[2][128 * 64];
    __shared__ alignas(16) bf16 sB[2][128 * 64];

    const int tid  = threadIdx.x;
    const int lane = tid & 63;
    const int w    = tid >> 6;      // 0..3
    const int wr   = w >> 1;        // wave row (0..1)
    const int wc   = w & 1;         // wave col (0..1)
    const int l15  = lane & 15;
    const int l4   = lane >> 4;
    const int mt   = M >> 7;                       // m-tiles
    const int cpx  = (int)gridDim.x >> 3;          // blocks per XCD chunk
    const int vb   = (blockIdx.x & 7) * cpx + (blockIdx.x >> 3);  // XCD-chunked
    const int m0   = (vb % mt) * 128;              // m fastest within chunk
    const int n0   = (vb / mt) * 128;

    f32x4 acc[4][4] = {};

    const int rsub = lane >> 3;                       // row within chunk (0..7)
    const int scol = ((lane & 7) * 8) ^ (rsub << 3);  // pre-swizzled source col

    auto stage = [&](int t, int buf) {
#pragma unroll
        for (int j = 0; j < 4; ++j) {
            const int c   = w * 4 + j;
            const int row = c * 8 + rsub;
            gload_lds16(A + (size_t)(m0 + row) * K + t * 64 + scol, &sA[buf][c * 512]);
            gload_lds16(B + (size_t)(n0 + row) * K + t * 64 + scol, &sB[buf][c * 512]);
        }
    };

    const int nt = K >> 6;   // K-tiles of 64

    stage(0, 0);
    __syncthreads();         // implicit vmcnt(0) drain

    int buf = 0;
    for (int t = 0; t < nt; ++t) {
        if (t + 1 < nt) stage(t + 1, buf ^ 1);   // prefetch hides under compute

        bf16x8 af[2][4], bfr[2][4];
#pragma unroll
        for (int kk = 0; kk < 2; ++kk) {
#pragma unroll
            for (int i = 0; i < 4; ++i) {
                const int ra = wr * 64 + i * 16 + l15;
                af[kk][i]  = *(const bf16x8*)&sA[buf][ra * 64 + ((kk * 32 + l4 * 8) ^ ((ra & 7) << 3))];
                const int rb = wc * 64 + i * 16 + l15;
                bfr[kk][i] = *(const bf16x8*)&sB[buf][rb * 64 + ((kk * 32 + l4 * 8) ^ ((rb & 7) << 3))];
            }
        }
#pragma unroll
        for (int kk = 0; kk < 2; ++kk)
#pragma unroll
            for (int i = 0; i < 4; ++i)
#pragma unroll
                for (int j = 0; j < 4; ++j)
                    acc[i][j] = __builtin_amdgcn_mfma_f32_16x16x32_bf16(af[kk][i], bfr[kk][j], acc[i][j], 0, 0, 0);

        __syncthreads();     // drains vmcnt (prefetch done); protects buf reuse
        buf ^= 1;
    }

    // epilogue: C/D layout col = lane&15, row = (lane>>4)*4 + reg
#pragma unroll
    for (int i = 0; i < 4; ++i) {
        const int row = m0 + wr * 64 + i * 16 + l4 * 4;
#pragma unroll
        for (int j = 0; j < 4; ++j) {
            const int col = n0 + wc * 64 + j * 16 + l15;
#pragma unroll
            for (int r = 0; r < 4; ++r)
                C[(size_t)(row + r) * N + col] = (OUT_T)acc[i][j][r];
        }
    }
}

// ---------------------------------------------------------------------------
// Flash attention, causal, GQA 4:1 (EXACT R9/R13 proven structure; FROZEN.
// Four restructures regressed: 4-wave variants (R7/R8: occupancy fell),
// shared-kb fusion (R10: +VGPR, lost cross-strip overlap), wave-split (R12:
// halved work per barrier interval), KVBLK=128 (R14: register spill to
// scratch -- FETCH 37->220MB). 8 waves/512 threads, strip pairing (b and
// 15-b, 128 rows each, uniform 34 tile-units/block), grid 8x32 = 256 blocks.
// Double-buffered K (gload_lds, pre-swizzled source) and V (reg-staged,
// transposed+swizzled write). One barrier per tile. No-max softmax; T5
// setprio on MFMA clusters.
__global__ __launch_bounds__(512) void attn_kernel(const bf16* __restrict__ Q,
                                                   const bf16* __restrict__ Kp,
                                                   const bf16* __restrict__ Vp,
                                                   bf16* __restrict__ O) {
    __shared__ alignas(16) bf16 sK[2][64 * 128];   // [s][d], elem col ^= (row&7)<<3
    __shared__ alignas(16) bf16 sVt[2][128 * 64];  // [d][s], elem col ^= (row&7)<<3
    __shared__ alignas(16) bf16 sP[8][16 * 64];    // per-wave, col ^= S2(row)<<3

    const int tid  = threadIdx.x;
    const int lane = tid & 63;
    const int w    = tid >> 6;       // 0..7
    const int l15  = lane & 15;
    const int l4   = lane >> 4;
    const int h    = blockIdx.y;
    const int hk   = h >> 2;
    const int b    = blockIdx.x;                 // 0..7
    const int qH   = 15 - b;                     // heavy strip
    const int qL   = b;                          // light strip
    const float C2 = 0.12751744f;                // scale * log2(e)

    const bf16* Kbase = Kp + hk * HD;
    const bf16* Vbase = Vp + hk * HD;

    // Q fragments for both strips (held in registers for whole kernel)
    const int rbH = qH * 128 + w * 16;
    const int rbL = qL * 128 + w * 16;
    bf16x8 qfH[4], qfL[4];
#pragma unroll
    for (int ks = 0; ks < 4; ++ks) {
        qfH[ks] = *(const bf16x8*)(Q + (size_t)(rbH + l15) * QLD + h * HD + ks * 32 + l4 * 8);
        qfL[ks] = *(const bf16x8*)(Q + (size_t)(rbL + l15) * QLD + h * HD + ks * 32 + l4 * 8);
    }

    f32x4 accH[8] = {}, accL[8] = {};
    float lH[4] = {0.f, 0.f, 0.f, 0.f}, lL[4] = {0.f, 0.f, 0.f, 0.f};

    // --- staging helpers (split across 8 waves) ---
    auto stageK = [&](int t, int buf) {
#pragma unroll
        for (int j = 0; j < 2; ++j) {
            const int c   = w * 2 + j;
            const int row = c * 4 + l4;
            const int col = (l15 * 8) ^ ((row & 7) << 3);
            gload_lds16(Kbase + (size_t)(t * 64 + row) * KVLD + col, &sK[buf][c * 512]);
        }
    };
    auto loadV = [&](int t, bf16x8* vr) {
#pragma unroll
        for (int r2 = 0; r2 < 2; ++r2) {
            const int c = r2 * 8 + w;
            vr[r2] = *(const bf16x8*)(Vbase + (size_t)(t * 64 + lane) * KVLD + c * 8);
        }
    };
    auto writeV = [&](const bf16x8* vr, int buf) {
#pragma unroll
        for (int r2 = 0; r2 < 2; ++r2) {
            const int c = r2 * 8 + w;
#pragma unroll
            for (int e = 0; e < 8; ++e) {
                const int row = c * 8 + e;                 // d-index; row&7 == e
                sVt[buf][row * 64 + (lane ^ (e << 3))] = vr[r2][e];
            }
        }
    };

    // --- one strip's QK^T/softmax/PV for one tile ---
    auto strip = [&](const bf16x8* qf, f32x4* acc_o, float* lrow,
                     int rbase, int s0, int cur) {
        if (s0 > rbase + 15) return;   // wave-uniform: rows entirely above tile
        // QK^T: this wave's 16 q-rows x all 64 s-cols (raw scores)
        f32x4 accs[4] = {};
        __builtin_amdgcn_s_setprio(1);
#pragma unroll
        for (int ks = 0; ks < 4; ++ks) {
#pragma unroll
            for (int j = 0; j < 4; ++j) {
                const int krow = j * 16 + l15;
                bf16x8 kb = *(const bf16x8*)&sK[cur][krow * 128 + ((ks * 32 + l4 * 8) ^ ((krow & 7) << 3))];
                accs[j] = __builtin_amdgcn_mfma_f32_16x16x32_bf16(qf[ks], kb, accs[j], 0, 0, 0);
            }
        }
        __builtin_amdgcn_s_setprio(0);

        // no-max softmax: p = exp2(raw*C2) (shift-invariant; raw bounded).
        float sc[4][4];
        float rsum[4] = {0.f, 0.f, 0.f, 0.f};
        const bool needMask = (s0 + 63 > rbase);   // wave-uniform
        if (needMask) {
#pragma unroll
            for (int j = 0; j < 4; ++j) {
                const int scol = s0 + j * 16 + l15;
#pragma unroll
                for (int i = 0; i < 4; ++i) {
                    const int r = rbase + l4 * 4 + i;
                    const float p = (scol > r) ? 0.f : exp2f(accs[j][i] * C2);
                    sc[j][i] = p;
                    rsum[i] += p;
                }
            }
        } else {
#pragma unroll
            for (int j = 0; j < 4; ++j)
#pragma unroll
                for (int i = 0; i < 4; ++i) {
                    const float p = exp2f(accs[j][i] * C2);
                    sc[j][i] = p;
                    rsum[i] += p;
                }
        }
        // row-sum reduce across the 16 lanes holding this row group
#pragma unroll
        for (int i = 0; i < 4; ++i) {
#pragma unroll
            for (int msk = 1; msk < 16; msk <<= 1)
                rsum[i] += __shfl_xor(rsum[i], msk);
            lrow[i] += rsum[i];
        }

        // P -> LDS (bf16), per-wave buffer (wave-private: no barrier needed)
#pragma unroll
        for (int j = 0; j < 4; ++j)
#pragma unroll
            for (int i = 0; i < 4; ++i) {
                const int prow = l4 * 4 + i;
                const int s2   = (prow & 7) ^ ((prow >> 3) << 1);
                sP[w][prow * 64 + ((j * 16 + l15) ^ (s2 << 3))] = (bf16)sc[j][i];
            }

        // PV: out[16][128] += P[16][64] * V[64][128]
        __builtin_amdgcn_s_setprio(1);
#pragma unroll
        for (int kk = 0; kk < 2; ++kk) {
            const int s2l = (l15 & 7) ^ ((l15 >> 3) << 1);
            bf16x8 pa = *(const bf16x8*)&sP[w][l15 * 64 + ((kk * 32 + l4 * 8) ^ (s2l << 3))];
#pragma unroll
            for (int d = 0; d < 8; ++d) {
                const int vrow = d * 16 + l15;
                bf16x8 vb = *(const bf16x8*)&sVt[cur][vrow * 64 + ((kk * 32 + l4 * 8) ^ ((vrow & 7) << 3))];
                acc_o[d] = __builtin_amdgcn_mfma_f32_16x16x32_bf16(pa, vb, acc_o[d], 0, 0, 0);
            }
        }
        __builtin_amdgcn_s_setprio(0);
    };

    const int ntH = 2 * qH + 2;   // tiles for heavy strip (= loop bound)
    const int ntL = 2 * qL + 2;   // tiles for light strip

    // prologue: stage tile 0 into buf 0
    bf16x8 vreg[2];
    loadV(0, vreg);
    stageK(0, 0);
    writeV(vreg, 0);
    __syncthreads();

    int cur = 0;
    for (int t = 0; t < ntH; ++t) {
        const int s0 = t * 64;
        const bool pf = (t + 1 < ntH);
        if (pf) {               // issue next-tile loads early (latency hides under compute)
            loadV(t + 1, vreg); // V first: its reg-use wait leaves K gload_lds in flight
            stageK(t + 1, cur ^ 1);
        }

        strip(qfH, accH, lH, rbH, s0, cur);
        if (t < ntL) strip(qfL, accL, lL, rbL, s0, cur);

        // write prefetched V into the other buffer (nobody reads it yet)
        if (pf) writeV(vreg, cur ^ 1);

        __syncthreads();   // drains vmcnt (K gload_lds) + lgkm; buffers swap
        cur ^= 1;
    }

    // epilogue: normalize (reciprocal) and store both strips
    float rH[4], rL[4];
#pragma unroll
    for (int i = 0; i < 4; ++i) { rH[i] = __frcp_rn(lH[i]); rL[i] = __frcp_rn(lL[i]); }
#pragma unroll
    for (int d = 0; d < 8; ++d)
#pragma unroll
        for (int i = 0; i < 4; ++i) {
            O[(size_t)(rbH + l4 * 4 + i) * HID + h * HD + d * 16 + l15] = (bf16)(accH[d][i] * rH[i]);
            O[(size_t)(rbL + l4 * 4 + i) * HID + h * HD + d * 16 + l15] = (bf16)(accL[d][i] * rL[i]);
        }
}

// ---------------------------------------------------------------------------
extern "C" void kernel_launch(void* const* d_in, const int* in_sizes, int n_in,
                              void* d_out, int out_size, void* d_ws, size_t ws_size,
                              hipStream_t stream) {
    const float* hx = (const float*)d_in[0];
    // d_in[1] = attention_mask (exact causal) -- applied analytically
    const float* wq = (const float*)d_in[2];
    const float* wk = (const float*)d_in[3];
    const float* wv = (const float*)d_in[4];
    const float* wo = (const float*)d_in[5];
    float* out = (float*)d_out;

    // workspace layout (bf16), 92.3 MB total:
    //   Xb/Ob : 2048*4096  (X for projections; overwritten by attn output O)
    //   Wqkv  : 6144*4096  (wq rows 0..4095 | wk 4096..5119 | wv 5120..6143;
    //                       later reused for wo)
    //   QKV   : 2048*6144  (Q cols 0..4095 | K 4096..5119 | V 5120..6143)
    bf16* Xb   = (bf16*)d_ws;            // also Ob after attn
    bf16* Wqkv = Xb + 8388608;
    bf16* QKV  = Wqkv + 25165824;

    auto cast = [&](const float* src, bf16* dst, int n) {
        int n4 = n / 4;
        int blocks = (n4 + 255) / 256;
        if (blocks > 2048) blocks = 2048;
        cast_f32_bf16<<<blocks, 256, 0, stream>>>(src, dst, n4);
    };

    cast(hx, Xb, 2048 * 4096);
    // merged wq|wk|wv cast: one launch into contiguous Wqkv
    cast3_f32_bf16<<<2048, 256, 0, stream>>>(wq, wk, wv, Wqkv,
                                             4194304, 1048576, 1048576);

    // single merged Q|K|V projection: N=6144, 768 blocks (XCD-chunked order)
    gemm_bt<bf16><<<dim3(768), 256, 0, stream>>>(Xb, Wqkv, QKV, 2048, 6144, 4096);

    // wo cast overwrites the (now dead) wq region
    cast(wo, Wqkv, 4096 * 4096);

    // attn reads QKV (stride 6144), writes O into Xb (X is dead now)
    attn_kernel<<<dim3(8, 32), 512, 0, stream>>>(QKV, QKV + 4096, QKV + 5120, Xb);

    gemm_bt<float><<<dim3(512), 256, 0, stream>>>(Xb, Wqkv, out, 2048, 4096, 4096);
}